// Round 9
// baseline (200.343 us; speedup 1.0000x reference)
//
#include <hip/hip_runtime.h>
#include <hip/hip_bf16.h>

#define FDIM 1024
#define BROWS 16384
#define DELTA_C 0.3f
#define LAMB_C 0.0005f

typedef __bf16 bf8v __attribute__((ext_vector_type(8)));
typedef float f4v __attribute__((ext_vector_type(4)));
typedef unsigned short u16;
typedef u16 u16x8 __attribute__((ext_vector_type(8)));

// ws layout (bytes):
//   0    : f32 wsf[16]     (0=hinge)
//   64   : f32 colsum[1024]  (wsf+16)
//   4160 : f32 pabs[128]
//   4672 : f32 psq[128]
//   8192 : f32 rowacc[16384]  (64KB)
//   131072 : wb2 bf16 tiled [128 jslot][1024 kcol][8]  (2MB)
//            wb2[(js*1024+kc)*8+e] = w[kc][js*8+e]   (B-operand of G = pn @ w^T)
#define WS_PABS_OFF 4160
#define WS_PSQ_OFF 4672
#define WS_ROWACC_OFF 8192
#define WS_WB_OFF 131072
#define WS_NEED ((size_t)WS_WB_OFF + (1u << 21))

__device__ __forceinline__ u16 f2bf(float f) {
  unsigned u = __builtin_bit_cast(unsigned, f);
  u += 0x7fffu + ((u >> 16) & 1u);
  return (u16)(u >> 16);
}

__device__ __forceinline__ void gload_lds16(const void* g, void* l) {
  __builtin_amdgcn_global_load_lds(
      (const __attribute__((address_space(1))) unsigned int*)g,
      (__attribute__((address_space(3))) unsigned int*)l, 16, 0, 0);
}

// ---- prep W: colsum, |w-I| partials, bf16 row-sliced tiling (no transpose) ----
__global__ __launch_bounds__(256) void prep_w(const float* __restrict__ w,
                                              float* __restrict__ colsum,
                                              float* __restrict__ pabs,
                                              float* __restrict__ psq,
                                              u16* __restrict__ wb2) {
  __shared__ u16 tile[8][1024];  // [row][col] bf16
  __shared__ float red[8];
  const int t = threadIdx.x;
  const int b = blockIdx.x;
  const int k0 = b * 8;  // w rows owned
  const int col = t * 4;

  float cs0 = 0.f, cs1 = 0.f, cs2 = 0.f, cs3 = 0.f;
  float aacc = 0.f, sacc = 0.f;
#pragma unroll
  for (int i = 0; i < 8; ++i) {
    const int gk = k0 + i;
    const float4 v = *(const float4*)(w + (size_t)gk * FDIM + col);
    ushort4 bb;
    bb.x = f2bf(v.x); bb.y = f2bf(v.y); bb.z = f2bf(v.z); bb.w = f2bf(v.w);
    *(ushort4*)(&tile[i][col]) = bb;
    cs0 += v.x; cs1 += v.y; cs2 += v.z; cs3 += v.w;
    const float d0 = v.x - (gk == col + 0 ? 1.f : 0.f);
    const float d1 = v.y - (gk == col + 1 ? 1.f : 0.f);
    const float d2 = v.z - (gk == col + 2 ? 1.f : 0.f);
    const float d3 = v.w - (gk == col + 3 ? 1.f : 0.f);
    aacc += fabsf(d0) + fabsf(d1) + fabsf(d2) + fabsf(d3);
    sacc += d0 * d0 + d1 * d1 + d2 * d2 + d3 * d3;
  }
  atomicAdd(&colsum[col + 0], cs0);
  atomicAdd(&colsum[col + 1], cs1);
  atomicAdd(&colsum[col + 2], cs2);
  atomicAdd(&colsum[col + 3], cs3);
#pragma unroll
  for (int off = 1; off < 64; off <<= 1) {
    aacc += __shfl_xor(aacc, off);
    sacc += __shfl_xor(sacc, off);
  }
  const int wv = t >> 6;
  if ((t & 63) == 0) { red[wv] = aacc; red[4 + wv] = sacc; }
  __syncthreads();
  if (t == 0) pabs[b] = red[0] + red[1] + red[2] + red[3];
  if (t == 1) psq[b] = red[4] + red[5] + red[6] + red[7];
  // wb2[(js*1024 + k0+i)*8 + e] = tile[i][js*8+e]  (row-contiguous reads)
#pragma unroll
  for (int q = 0; q < 4; ++q) {
    const int idx = q * 256 + t;   // 0..1023
    const int i = idx >> 7;        // 0..7
    const int js = idx & 127;
    const u16x8 pk = *(const u16x8*)&tile[i][js * 8];
    *(u16x8*)(wb2 + ((size_t)js * FDIM + k0 + i) * 8) = pk;
  }
}

// ---- main: G = (imgp-imgn) @ w^T, BM=256 BN=128 BK=32, 2-buffer, T14 split ----
// 512 threads = 8 waves (4M x 2N), per-wave 64x64 output.
// Per buffer (24KB): A [4 jslot][256 m][16B] = 16K; B [4][128][16B] = 8K.
// Epilogue: rowacc += -2 * dot(skt_row, G_row); S2 accumulated during staging.
template <bool PRE>
__global__ __launch_bounds__(512, 4) void hofel_main(
    const float* __restrict__ skt, const float* __restrict__ imgp,
    const float* __restrict__ imgn, const float* __restrict__ w,
    const u16* __restrict__ wb2, const float* __restrict__ colsum,
    float* __restrict__ rowacc) {
  __shared__ u16 ldsT[2][12288];  // 2 x 24KB; reused as epilogue scratch
  __shared__ float lds_cs[FDIM];  // full colsum (only nt==0 blocks use it)

  const int t = threadIdx.x;
  const int lane = t & 63;
  const int wid = t >> 6;  // 0..7
  const int l15 = lane & 15;
  const int l4 = lane >> 4;

  // XCD swizzle: all 8 nt-blocks of one mt land on the same XCD (pn L2 reuse)
  const int swz = (blockIdx.x & 7) * 64 + (blockIdx.x >> 3);
  const int mt = swz >> 3, nt = swz & 7;
  const int m0 = mt * 256, n0 = nt * 128;

  const int wr = wid >> 1, wc = wid & 1;
  const int wm = wr * 64, wn = wc * 64;

  const int sm = t >> 1, sh = t & 1;     // staging: row m0+sm, k-half sh
  const bool do_s2 = (nt == 0);
  float s2 = 0.f;

  f4v acc[4][4];
#pragma unroll
  for (int mi = 0; mi < 4; ++mi)
#pragma unroll
    for (int ni = 0; ni < 4; ++ni) {
      f4v z = {0.f, 0.f, 0.f, 0.f};
      acc[mi][ni] = z;
    }

  float4 P[4], Q[4];  // staged imgp/imgn regs (T14: issue-early, convert-late)

  auto stage_load = [&](int kt) {
    const size_t ro = (size_t)(m0 + sm) * FDIM + kt * 32 + sh * 16;
    const float* pp = imgp + ro;
    const float* qq = imgn + ro;
#pragma unroll
    for (int i = 0; i < 4; ++i) P[i] = *(const float4*)(pp + i * 4);
#pragma unroll
    for (int i = 0; i < 4; ++i) Q[i] = *(const float4*)(qq + i * 4);
  };

  auto stageB = [&](int buf, int kt) {
    if constexpr (PRE) {
      const int o = wid * 1024;            // wave-uniform
      const int ol = o + lane * 16;
      const int s = ol >> 11;
      const int n = (ol >> 4) & 127;
      gload_lds16((const char*)(wb2 + ((size_t)(kt * 4 + s) * FDIM + n0 + n) * 8),
                  (char*)ldsT[buf] + 16384 + o);
    } else {
      // stage B from w directly: ldsB[s][kc][e] = w[n0+kc][kt*32+s*8+e]
      const int kc = t >> 2, s = t & 3;
      const float* wr_ = w + (size_t)(n0 + kc) * FDIM + kt * 32 + s * 8;
      const float4 a = *(const float4*)(wr_);
      const float4 b = *(const float4*)(wr_ + 4);
      u16x8 pk;
      pk[0] = f2bf(a.x); pk[1] = f2bf(a.y); pk[2] = f2bf(a.z); pk[3] = f2bf(a.w);
      pk[4] = f2bf(b.x); pk[5] = f2bf(b.y); pk[6] = f2bf(b.z); pk[7] = f2bf(b.w);
      *(u16x8*)((char*)ldsT[buf] + 16384 + (s * 128 + kc) * 16) = pk;
    }
  };

  auto stage_write = [&](int buf, int kt) {
    float pn[16];
#pragma unroll
    for (int i = 0; i < 4; ++i) {
      pn[i * 4 + 0] = P[i].x - Q[i].x;
      pn[i * 4 + 1] = P[i].y - Q[i].y;
      pn[i * 4 + 2] = P[i].z - Q[i].z;
      pn[i * 4 + 3] = P[i].w - Q[i].w;
    }
    u16x8 w0, w1;
#pragma unroll
    for (int e = 0; e < 8; ++e) { w0[e] = f2bf(pn[e]); w1[e] = f2bf(pn[8 + e]); }
    *(u16x8*)((char*)ldsT[buf] + (sh * 2 + 0) * 4096 + sm * 16) = w0;
    *(u16x8*)((char*)ldsT[buf] + (sh * 2 + 1) * 4096 + sm * 16) = w1;
    if (do_s2) {
      const int c0 = kt * 32 + sh * 16;
#pragma unroll
      for (int i = 0; i < 4; ++i) {
        const f4v cs = *(const f4v*)&lds_cs[c0 + i * 4];
        s2 += pn[i * 4 + 0] * (P[i].x + Q[i].x) * cs[0];
        s2 += pn[i * 4 + 1] * (P[i].y + Q[i].y) * cs[1];
        s2 += pn[i * 4 + 2] * (P[i].z + Q[i].z) * cs[2];
        s2 += pn[i * 4 + 3] * (P[i].w + Q[i].w) * cs[3];
      }
    }
  };

  // ---- prologue ----
  if (do_s2) { lds_cs[t] = colsum[t]; lds_cs[t + 512] = colsum[t + 512]; }
  stage_load(0);
  stageB(0, 0);
  __syncthreads();          // lds_cs visible (and orders nothing else harmful)
  stage_write(0, 0);
  __syncthreads();          // tile 0 ready (drains vmcnt+lgkm)

  int cur = 0;
  for (int kt = 0; kt < 32; ++kt) {
    if (kt < 31) { stage_load(kt + 1); stageB(cur ^ 1, kt + 1); }

    const char* bufb = (const char*)ldsT[cur];
    bf8v aF[4], bF[4];
#pragma unroll
    for (int mi = 0; mi < 4; ++mi)
      aF[mi] = *(const bf8v*)(bufb + l4 * 4096 + (wm + mi * 16 + l15) * 16);
#pragma unroll
    for (int ni = 0; ni < 4; ++ni)
      bF[ni] = *(const bf8v*)(bufb + 16384 + l4 * 2048 + (wn + ni * 16 + l15) * 16);
#pragma unroll
    for (int mi = 0; mi < 4; ++mi)
#pragma unroll
      for (int ni = 0; ni < 4; ++ni)
        acc[mi][ni] = __builtin_amdgcn_mfma_f32_16x16x32_bf16(aF[mi], bF[ni], acc[mi][ni], 0, 0, 0);

    if (kt < 31) stage_write(cur ^ 1, kt + 1);  // vmcnt wait lands here, after MFMAs
    __syncthreads();
    cur ^= 1;
  }

  // S2 per-row contribution (nt==0 blocks; 2 threads per row)
  if (do_s2) atomicAdd(rowacc + m0 + sm, s2);

  // ---- epilogue: rowacc += -2 * dot(skt_row[n0+wn .. +64], G_row) ----
  {
    float(*eT)[68] = (float(*)[68])((char*)ldsT + wid * 4352);  // per-wave 16x68 f32
    const int r = l15;
    const int qb = l4;
#pragma unroll
    for (int mi = 0; mi < 4; ++mi) {
#pragma unroll
      for (int ni = 0; ni < 4; ++ni)
#pragma unroll
        for (int rr = 0; rr < 4; ++rr)
          eT[l4 * 4 + rr][ni * 16 + l15] = acc[mi][ni][rr];
      const int rowg = m0 + wm + mi * 16 + r;
      const float* sr = skt + (size_t)rowg * FDIM + n0 + wn;
      float part = 0.f;
#pragma unroll
      for (int i = 0; i < 4; ++i) {
        const int q = qb + 4 * i;
        const f4v T = *(const f4v*)&eT[r][q * 4];
        const float4 s4 = *(const float4*)(sr + q * 4);
        part += T[0] * s4.x + T[1] * s4.y + T[2] * s4.z + T[3] * s4.w;
      }
      part += __shfl_xor(part, 16);
      part += __shfl_xor(part, 32);
      if (lane < 16) atomicAdd(rowacc + rowg, -2.f * part);
    }
  }
}

__global__ __launch_bounds__(1024) void hinge_reduce(const float* __restrict__ rowacc,
                                                     float* __restrict__ wsf) {
  __shared__ float part[16];
  const int t = threadIdx.x;
  const int id = blockIdx.x * 1024 + t;
  float v = fmaxf(DELTA_C + rowacc[id], 0.f);
#pragma unroll
  for (int off = 1; off < 64; off <<= 1) v += __shfl_xor(v, off);
  if ((t & 63) == 0) part[t >> 6] = v;
  __syncthreads();
  if (t < 16) {
    float x = part[t];
#pragma unroll
    for (int off = 1; off < 16; off <<= 1) x += __shfl_xor(x, off);
    if (t == 0) atomicAdd(&wsf[0], x);
  }
}

__global__ __launch_bounds__(128) void finalize_k(const float* __restrict__ wsf,
                                                  const float* __restrict__ pabs,
                                                  const float* __restrict__ psq,
                                                  float* __restrict__ out) {
  __shared__ float ra[2], rs[2];
  const int t = threadIdx.x;
  float a = pabs[t], s = psq[t];
#pragma unroll
  for (int off = 1; off < 64; off <<= 1) {
    a += __shfl_xor(a, off);
    s += __shfl_xor(s, off);
  }
  if ((t & 63) == 0) { ra[t >> 6] = a; rs[t >> 6] = s; }
  __syncthreads();
  if (t == 0)
    out[0] = wsf[0] * (1.f / (float)BROWS) +
             LAMB_C * ((ra[0] + ra[1]) + sqrtf(rs[0] + rs[1]));
}

extern "C" void kernel_launch(void* const* d_in, const int* in_sizes, int n_in,
                              void* d_out, int out_size, void* d_ws, size_t ws_size,
                              hipStream_t stream) {
  const float* skt  = (const float*)d_in[0];
  const float* imgp = (const float*)d_in[1];
  const float* imgn = (const float*)d_in[2];
  const float* w    = (const float*)d_in[3];

  float* wsf = (float*)d_ws;
  float* colsum = wsf + 16;
  float* pabs = (float*)((char*)d_ws + WS_PABS_OFF);
  float* psq = (float*)((char*)d_ws + WS_PSQ_OFF);
  float* rowacc = (float*)((char*)d_ws + WS_ROWACC_OFF);
  u16* wb2 = (u16*)((char*)d_ws + WS_WB_OFF);
  float* out = (float*)d_out;

  // zero wsf + colsum + pabs/psq + rowacc every call (harness doesn't re-poison)
  hipMemsetAsync(d_ws, 0, WS_ROWACC_OFF + BROWS * sizeof(float), stream);

  prep_w<<<128, 256, 0, stream>>>(w, colsum, pabs, psq, wb2);

  if (ws_size >= WS_NEED) {
    hofel_main<true><<<512, 512, 0, stream>>>(skt, imgp, imgn, w, wb2, colsum, rowacc);
  } else {
    hofel_main<false><<<512, 512, 0, stream>>>(skt, imgp, imgn, w, wb2, colsum, rowacc);
  }

  hinge_reduce<<<16, 1024, 0, stream>>>(rowacc, wsf);
  finalize_k<<<1, 128, 0, stream>>>(wsf, pabs, psq, out);
}

// Round 11
// 137.620 us; speedup vs baseline: 1.4558x; 1.4558x over previous
//
#include <hip/hip_runtime.h>
#include <hip/hip_bf16.h>

#define FDIM 1024
#define BROWS 16384
#define DELTA_C 0.3f
#define LAMB_C 0.0005f

typedef __bf16 bf8v __attribute__((ext_vector_type(8)));
typedef float f4v __attribute__((ext_vector_type(4)));
typedef unsigned short u16;
typedef u16 u16x8 __attribute__((ext_vector_type(8)));

// ws layout (bytes):
//   0    : f32 wsf[16]     (0=hinge)
//   64   : f32 colsum[1024]  (wsf+16)
//   4160 : f32 pabs[128]
//   4672 : f32 psq[128]
//   8192 : f32 rowacc[16384]  (64KB)
//   131072 : wb  bf16 tiled [128 kslot][1024 n][8]   (2MB)  wb[(ks*1024+n)*8+e] = w[ks*8+e][n]
//   131072+2MB : sktb bf16 tiled [128 kslot][16384 m][8] (32MB) sktb[(ks*16384+m)*8+e] = skt[m][ks*8+e]
#define WS_PABS_OFF 4160
#define WS_PSQ_OFF 4672
#define WS_ROWACC_OFF 8192
#define WS_WB_OFF 131072
#define WS_SKTB_OFF (131072 + (1u << 21))
#define WS_NEED_FULL ((size_t)WS_SKTB_OFF + ((size_t)1 << 25))

__device__ __forceinline__ u16 f2bf(float f) {
  unsigned u = __builtin_bit_cast(unsigned, f);
  u += 0x7fffu + ((u >> 16) & 1u);
  return (u16)(u >> 16);
}

// ---- merged prep: blocks [0,128) do W; blocks [128, 128+2048) do A ----
// (validated r4-r8)
template <bool DO_A>
__global__ __launch_bounds__(256) void prep_all(const float* __restrict__ w,
                                                const float* __restrict__ skt,
                                                float* __restrict__ colsum,
                                                float* __restrict__ pabs,
                                                float* __restrict__ psq,
                                                u16* __restrict__ wb,
                                                u16* __restrict__ sktb) {
  __shared__ char smem_u[17440];
  const int t = threadIdx.x;
  const int bid = blockIdx.x;

  if (bid < 128) {
    u16(*tile)[1024] = (u16(*)[1024])smem_u;  // 16KB
    float* red = (float*)(smem_u + 16384);
    const int b = bid;
    const int k0 = b * 8;
    const int col = t * 4;

    float cs0 = 0.f, cs1 = 0.f, cs2 = 0.f, cs3 = 0.f;
    float aacc = 0.f, sacc = 0.f;
#pragma unroll
    for (int i = 0; i < 8; ++i) {
      const int gk = k0 + i;
      const float4 v = *(const float4*)(w + (size_t)gk * FDIM + col);
      ushort4 bb;
      bb.x = f2bf(v.x); bb.y = f2bf(v.y); bb.z = f2bf(v.z); bb.w = f2bf(v.w);
      *(ushort4*)(&tile[i][col]) = bb;
      cs0 += v.x; cs1 += v.y; cs2 += v.z; cs3 += v.w;
      const float d0 = v.x - (gk == col + 0 ? 1.f : 0.f);
      const float d1 = v.y - (gk == col + 1 ? 1.f : 0.f);
      const float d2 = v.z - (gk == col + 2 ? 1.f : 0.f);
      const float d3 = v.w - (gk == col + 3 ? 1.f : 0.f);
      aacc += fabsf(d0) + fabsf(d1) + fabsf(d2) + fabsf(d3);
      sacc += d0 * d0 + d1 * d1 + d2 * d2 + d3 * d3;
    }
    atomicAdd(&colsum[col + 0], cs0);
    atomicAdd(&colsum[col + 1], cs1);
    atomicAdd(&colsum[col + 2], cs2);
    atomicAdd(&colsum[col + 3], cs3);
#pragma unroll
    for (int off = 1; off < 64; off <<= 1) {
      aacc += __shfl_xor(aacc, off);
      sacc += __shfl_xor(sacc, off);
    }
    const int wv = t >> 6;
    if ((t & 63) == 0) { red[wv] = aacc; red[4 + wv] = sacc; }
    __syncthreads();
    if (t == 0) pabs[b] = red[0] + red[1] + red[2] + red[3];
    if (t == 1) psq[b] = red[4] + red[5] + red[6] + red[7];
#pragma unroll
    for (int j = 0; j < 4; ++j) {
      const int n = col + j;
      u16x8 pk;
#pragma unroll
      for (int e = 0; e < 8; ++e) pk[e] = tile[e][n];
      *(u16x8*)(wb + ((size_t)b * FDIM + n) * 8) = pk;
    }
  } else if constexpr (DO_A) {
    u16(*tile)[136] = (u16(*)[136])smem_u;  // 64 x 136 u16
    const int ab = bid - 128;
    const int mb = ab >> 3;
    const int kb = ab & 7;
    const int m0 = mb * 64, k0 = kb * 128;
#pragma unroll
    for (int i = 0; i < 8; ++i) {
      const int fid = i * 256 + t;
      const int ml = fid >> 5;
      const int c4 = fid & 31;
      const float4 v = *(const float4*)(skt + (size_t)(m0 + ml) * FDIM + k0 + c4 * 4);
      ushort4 b;
      b.x = f2bf(v.x); b.y = f2bf(v.y); b.z = f2bf(v.z); b.w = f2bf(v.w);
      *(ushort4*)(&tile[ml][c4 * 4]) = b;
    }
    __syncthreads();
    const int ks0 = k0 >> 3;
#pragma unroll
    for (int i = 0; i < 4; ++i) {
      const int uid = i * 256 + t;
      const int si = uid >> 6;
      const int ml = uid & 63;
      const u16x8 pk = *(const u16x8*)(&tile[ml][si * 8]);
      *(u16x8*)(sktb + ((size_t)(ks0 + si) * BROWS + m0 + ml) * 8) = pk;
    }
  }
}

// ---- main: T = skt @ w. NO LDS, NO BARRIERS in the loop.
// 4096 independent waves; each owns a 64x64 output tile and loads its MFMA
// fragments directly global->VGPR from the fragment-ordered sktb/wb,
// double-buffered in named registers.
template <bool PRE>
__global__ __launch_bounds__(256, 3) void hofel_main(
    const float* __restrict__ skt, const float* __restrict__ imgp,
    const float* __restrict__ imgn, const float* __restrict__ w,
    const u16* __restrict__ wb, const u16* __restrict__ sktb,
    const float* __restrict__ colsum, float* __restrict__ rowacc) {
  __shared__ float eT_all[4][16][68];  // per-wave epilogue scratch (17408B)

  const int t = threadIdx.x;
  const int lane = t & 63;
  const int wid = t >> 6;  // 0..3
  const int l15 = lane & 15;
  const int l4 = lane >> 4;

  // XCD-contiguous tile map: XCD x owns mt in [x*32, x*32+32)
  const int x = blockIdx.x & 7;
  const int b = blockIdx.x >> 3;        // 0..127
  const int tid = b * 4 + wid;          // 0..511
  const int mt = x * 32 + (tid >> 4);   // 0..255
  const int ntw = tid & 15;             // 0..15
  const int m0 = mt * 64, n0 = ntw * 64;

  f4v acc[4][4];
#pragma unroll
  for (int mi = 0; mi < 4; ++mi)
#pragma unroll
    for (int ni = 0; ni < 4; ++ni) {
      f4v z = {0.f, 0.f, 0.f, 0.f};
      acc[mi][ni] = z;
    }

  // fragment base pointers (PRE path): lane (l4,l15) of fragment (mi|ni)
  const u16* aBase = sktb + ((size_t)l4 * BROWS + m0 + l15) * 8;
  const u16* bBase = wb + ((size_t)l4 * FDIM + n0 + l15) * 8;

  auto load_frags = [&](int kt, bf8v& A0, bf8v& A1, bf8v& A2, bf8v& A3,
                        bf8v& B0, bf8v& B1, bf8v& B2, bf8v& B3) {
    if constexpr (PRE) {
      const u16* ap = aBase + (size_t)kt * (4u * BROWS * 8u);
      const u16* bp = bBase + (size_t)kt * (4u * FDIM * 8u);
      A0 = *(const bf8v*)(ap);        A1 = *(const bf8v*)(ap + 128);
      A2 = *(const bf8v*)(ap + 256);  A3 = *(const bf8v*)(ap + 384);
      B0 = *(const bf8v*)(bp);        B1 = *(const bf8v*)(bp + 128);
      B2 = *(const bf8v*)(bp + 256);  B3 = *(const bf8v*)(bp + 384);
    } else {
      // correctness fallback (no workspace): build fragments from f32 inputs
      const int k0f = kt * 32 + l4 * 8;
      bf8v* Aout[4] = {&A0, &A1, &A2, &A3};
      bf8v* Bout[4] = {&B0, &B1, &B2, &B3};
#pragma unroll
      for (int mi = 0; mi < 4; ++mi) {
        const float* p = skt + (size_t)(m0 + mi * 16 + l15) * FDIM + k0f;
        const float4 u0 = *(const float4*)p;
        const float4 u1 = *(const float4*)(p + 4);
        u16x8 pk;
        pk[0] = f2bf(u0.x); pk[1] = f2bf(u0.y); pk[2] = f2bf(u0.z); pk[3] = f2bf(u0.w);
        pk[4] = f2bf(u1.x); pk[5] = f2bf(u1.y); pk[6] = f2bf(u1.z); pk[7] = f2bf(u1.w);
        *Aout[mi] = __builtin_bit_cast(bf8v, pk);
      }
#pragma unroll
      for (int ni = 0; ni < 4; ++ni) {
        const int n = n0 + ni * 16 + l15;
        u16x8 pk;
#pragma unroll
        for (int e = 0; e < 8; ++e) pk[e] = f2bf(w[(size_t)(k0f + e) * FDIM + n]);
        *Bout[ni] = __builtin_bit_cast(bf8v, pk);
      }
    }
  };

#define MMSET(A0, A1, A2, A3, B0, B1, B2, B3)                                        \
  do {                                                                               \
    acc[0][0] = __builtin_amdgcn_mfma_f32_16x16x32_bf16(A0, B0, acc[0][0], 0, 0, 0); \
    acc[0][1] = __builtin_amdgcn_mfma_f32_16x16x32_bf16(A0, B1, acc[0][1], 0, 0, 0); \
    acc[0][2] = __builtin_amdgcn_mfma_f32_16x16x32_bf16(A0, B2, acc[0][2], 0, 0, 0); \
    acc[0][3] = __builtin_amdgcn_mfma_f32_16x16x32_bf16(A0, B3, acc[0][3], 0, 0, 0); \
    acc[1][0] = __builtin_amdgcn_mfma_f32_16x16x32_bf16(A1, B0, acc[1][0], 0, 0, 0); \
    acc[1][1] = __builtin_amdgcn_mfma_f32_16x16x32_bf16(A1, B1, acc[1][1], 0, 0, 0); \
    acc[1][2] = __builtin_amdgcn_mfma_f32_16x16x32_bf16(A1, B2, acc[1][2], 0, 0, 0); \
    acc[1][3] = __builtin_amdgcn_mfma_f32_16x16x32_bf16(A1, B3, acc[1][3], 0, 0, 0); \
    acc[2][0] = __builtin_amdgcn_mfma_f32_16x16x32_bf16(A2, B0, acc[2][0], 0, 0, 0); \
    acc[2][1] = __builtin_amdgcn_mfma_f32_16x16x32_bf16(A2, B1, acc[2][1], 0, 0, 0); \
    acc[2][2] = __builtin_amdgcn_mfma_f32_16x16x32_bf16(A2, B2, acc[2][2], 0, 0, 0); \
    acc[2][3] = __builtin_amdgcn_mfma_f32_16x16x32_bf16(A2, B3, acc[2][3], 0, 0, 0); \
    acc[3][0] = __builtin_amdgcn_mfma_f32_16x16x32_bf16(A3, B0, acc[3][0], 0, 0, 0); \
    acc[3][1] = __builtin_amdgcn_mfma_f32_16x16x32_bf16(A3, B1, acc[3][1], 0, 0, 0); \
    acc[3][2] = __builtin_amdgcn_mfma_f32_16x16x32_bf16(A3, B2, acc[3][2], 0, 0, 0); \
    acc[3][3] = __builtin_amdgcn_mfma_f32_16x16x32_bf16(A3, B3, acc[3][3], 0, 0, 0); \
  } while (0)

  {
    bf8v a00, a01, a02, a03, b00, b01, b02, b03;  // set 0
    bf8v a10, a11, a12, a13, b10, b11, b12, b13;  // set 1
    load_frags(0, a00, a01, a02, a03, b00, b01, b02, b03);
#pragma unroll
    for (int kt = 0; kt < 30; kt += 2) {
      load_frags(kt + 1, a10, a11, a12, a13, b10, b11, b12, b13);
      MMSET(a00, a01, a02, a03, b00, b01, b02, b03);
      load_frags(kt + 2, a00, a01, a02, a03, b00, b01, b02, b03);
      MMSET(a10, a11, a12, a13, b10, b11, b12, b13);
    }
    load_frags(31, a10, a11, a12, a13, b10, b11, b12, b13);
    MMSET(a00, a01, a02, a03, b00, b01, b02, b03);  // kt=30
    MMSET(a10, a11, a12, a13, b10, b11, b12, b13);  // kt=31
  }
#undef MMSET

  // ---- epilogue (r8-validated): per-wave LDS transpose -> coalesced f4 reads
  // rowacc[row] += sum_c (p-n)*(-2*T + (p+n)*colsum[c]),  c in [n0, n0+64)
  {
    float(*eT)[68] = eT_all[wid];
#pragma unroll
    for (int mi = 0; mi < 4; ++mi) {
#pragma unroll
      for (int ni = 0; ni < 4; ++ni)
#pragma unroll
        for (int rr = 0; rr < 4; ++rr)
          eT[l4 * 4 + rr][ni * 16 + l15] = acc[mi][ni][rr];
      // within-wave LDS RAW: compiler inserts the lgkm wait; no barrier needed
      const int rowg = m0 + mi * 16 + l15;
      const float* pr = imgp + (size_t)rowg * FDIM + n0;
      const float* nr = imgn + (size_t)rowg * FDIM + n0;
      float part = 0.f;
#pragma unroll
      for (int i = 0; i < 4; ++i) {
        const int q = l4 + 4 * i;  // col-quad 0..15
        const f4v T = *(const f4v*)&eT[l15][q * 4];
        const float4 p = *(const float4*)(pr + q * 4);
        const float4 n = *(const float4*)(nr + q * 4);
        const float4 cs = *(const float4*)(colsum + n0 + q * 4);
        part += (p.x - n.x) * (-2.f * T[0] + (p.x + n.x) * cs.x);
        part += (p.y - n.y) * (-2.f * T[1] + (p.y + n.y) * cs.y);
        part += (p.z - n.z) * (-2.f * T[2] + (p.z + n.z) * cs.z);
        part += (p.w - n.w) * (-2.f * T[3] + (p.w + n.w) * cs.w);
      }
      part += __shfl_xor(part, 16);
      part += __shfl_xor(part, 32);
      if (lane < 16) atomicAdd(rowacc + rowg, part);
    }
  }
}

__global__ __launch_bounds__(1024) void hinge_reduce(const float* __restrict__ rowacc,
                                                     float* __restrict__ wsf) {
  __shared__ float part[16];
  const int t = threadIdx.x;
  const int id = blockIdx.x * 1024 + t;
  float v = fmaxf(DELTA_C + rowacc[id], 0.f);
#pragma unroll
  for (int off = 1; off < 64; off <<= 1) v += __shfl_xor(v, off);
  if ((t & 63) == 0) part[t >> 6] = v;
  __syncthreads();
  if (t < 16) {
    float x = part[t];
#pragma unroll
    for (int off = 1; off < 16; off <<= 1) x += __shfl_xor(x, off);
    if (t == 0) atomicAdd(&wsf[0], x);
  }
}

__global__ __launch_bounds__(128) void finalize_k(const float* __restrict__ wsf,
                                                  const float* __restrict__ pabs,
                                                  const float* __restrict__ psq,
                                                  float* __restrict__ out) {
  __shared__ float ra[2], rs[2];
  const int t = threadIdx.x;
  float a = pabs[t], s = psq[t];
#pragma unroll
  for (int off = 1; off < 64; off <<= 1) {
    a += __shfl_xor(a, off);
    s += __shfl_xor(s, off);
  }
  if ((t & 63) == 0) { ra[t >> 6] = a; rs[t >> 6] = s; }
  __syncthreads();
  if (t == 0)
    out[0] = wsf[0] * (1.f / (float)BROWS) +
             LAMB_C * ((ra[0] + ra[1]) + sqrtf(rs[0] + rs[1]));
}

extern "C" void kernel_launch(void* const* d_in, const int* in_sizes, int n_in,
                              void* d_out, int out_size, void* d_ws, size_t ws_size,
                              hipStream_t stream) {
  const float* skt  = (const float*)d_in[0];
  const float* imgp = (const float*)d_in[1];
  const float* imgn = (const float*)d_in[2];
  const float* w    = (const float*)d_in[3];

  float* wsf = (float*)d_ws;
  float* colsum = wsf + 16;
  float* pabs = (float*)((char*)d_ws + WS_PABS_OFF);
  float* psq = (float*)((char*)d_ws + WS_PSQ_OFF);
  float* rowacc = (float*)((char*)d_ws + WS_ROWACC_OFF);
  u16* wb = (u16*)((char*)d_ws + WS_WB_OFF);
  u16* sktb = (u16*)((char*)d_ws + WS_SKTB_OFF);
  float* out = (float*)d_out;

  // zero wsf + colsum + pabs/psq + rowacc every call (harness doesn't re-poison)
  hipMemsetAsync(d_ws, 0, WS_ROWACC_OFF + BROWS * sizeof(float), stream);

  if (ws_size >= WS_NEED_FULL) {
    prep_all<true><<<128 + 2048, 256, 0, stream>>>(w, skt, colsum, pabs, psq, wb, sktb);
    hofel_main<true><<<1024, 256, 0, stream>>>(skt, imgp, imgn, w, wb, sktb, colsum, rowacc);
  } else {
    prep_all<false><<<128, 256, 0, stream>>>(w, skt, colsum, pabs, psq, wb, sktb);
    hofel_main<false><<<1024, 256, 0, stream>>>(skt, imgp, imgn, w, wb, sktb, colsum, rowacc);
  }

  hinge_reduce<<<16, 1024, 0, stream>>>(rowacc, wsf);
  finalize_k<<<1, 128, 0, stream>>>(wsf, pabs, psq, out);
}

// Round 12
// 94.322 us; speedup vs baseline: 2.1240x; 1.4590x over previous
//
#include <hip/hip_runtime.h>
#include <hip/hip_bf16.h>

#define FDIM 1024
#define BROWS 16384
#define DELTA_C 0.3f
#define LAMB_C 0.0005f

typedef __bf16 bf8v __attribute__((ext_vector_type(8)));
typedef float f4v __attribute__((ext_vector_type(4)));
typedef unsigned short u16;
typedef u16 u16x8 __attribute__((ext_vector_type(8)));

// ws layout (bytes):
//   0    : f32 wsf[16]     (0=hinge)
//   64   : f32 colsum[1024]  (wsf+16)
//   4160 : f32 pabs[128]
//   4672 : f32 psq[128]
//   8192 : f32 rowacc[16384]  (64KB)
//   131072 : wb  bf16 tiled [128 kslot][1024 n][8]  (2MB)  wb[(ks*1024+n)*8+e] = w[ks*8+e][n]
#define WS_PABS_OFF 4160
#define WS_PSQ_OFF 4672
#define WS_ROWACC_OFF 8192
#define WS_WB_OFF 131072
#define WS_NEED ((size_t)WS_WB_OFF + (1u << 21))

__device__ __forceinline__ u16 f2bf(float f) {
  unsigned u = __builtin_bit_cast(unsigned, f);
  u += 0x7fffu + ((u >> 16) & 1u);
  return (u16)(u >> 16);
}

__device__ __forceinline__ void gload_lds16(const void* g, void* l) {
  __builtin_amdgcn_global_load_lds(
      (const __attribute__((address_space(1))) unsigned int*)g,
      (__attribute__((address_space(3))) unsigned int*)l, 16, 0, 0);
}

// ---- prep W (validated r4-r8): colsum, |w-I| partials, wb fragment tiling ----
__global__ __launch_bounds__(256) void prep_w(const float* __restrict__ w,
                                              float* __restrict__ colsum,
                                              float* __restrict__ pabs,
                                              float* __restrict__ psq,
                                              u16* __restrict__ wb) {
  __shared__ u16 tile[8][1024];  // 16KB
  __shared__ float red[8];
  const int t = threadIdx.x;
  const int b = blockIdx.x;  // kslot 0..127
  const int k0 = b * 8;
  const int col = t * 4;

  float cs0 = 0.f, cs1 = 0.f, cs2 = 0.f, cs3 = 0.f;
  float aacc = 0.f, sacc = 0.f;
#pragma unroll
  for (int i = 0; i < 8; ++i) {
    const int gk = k0 + i;
    const float4 v = *(const float4*)(w + (size_t)gk * FDIM + col);
    ushort4 bb;
    bb.x = f2bf(v.x); bb.y = f2bf(v.y); bb.z = f2bf(v.z); bb.w = f2bf(v.w);
    *(ushort4*)(&tile[i][col]) = bb;
    cs0 += v.x; cs1 += v.y; cs2 += v.z; cs3 += v.w;
    const float d0 = v.x - (gk == col + 0 ? 1.f : 0.f);
    const float d1 = v.y - (gk == col + 1 ? 1.f : 0.f);
    const float d2 = v.z - (gk == col + 2 ? 1.f : 0.f);
    const float d3 = v.w - (gk == col + 3 ? 1.f : 0.f);
    aacc += fabsf(d0) + fabsf(d1) + fabsf(d2) + fabsf(d3);
    sacc += d0 * d0 + d1 * d1 + d2 * d2 + d3 * d3;
  }
  atomicAdd(&colsum[col + 0], cs0);
  atomicAdd(&colsum[col + 1], cs1);
  atomicAdd(&colsum[col + 2], cs2);
  atomicAdd(&colsum[col + 3], cs3);
#pragma unroll
  for (int off = 1; off < 64; off <<= 1) {
    aacc += __shfl_xor(aacc, off);
    sacc += __shfl_xor(sacc, off);
  }
  const int wv = t >> 6;
  if ((t & 63) == 0) { red[wv] = aacc; red[4 + wv] = sacc; }
  __syncthreads();
  if (t == 0) pabs[b] = red[0] + red[1] + red[2] + red[3];
  if (t == 1) psq[b] = red[4] + red[5] + red[6] + red[7];
#pragma unroll
  for (int j = 0; j < 4; ++j) {
    const int n = col + j;
    u16x8 pk;
#pragma unroll
    for (int e = 0; e < 8; ++e) pk[e] = tile[e][n];
    *(u16x8*)(wb + ((size_t)b * FDIM + n) * 8) = pk;
  }
}

// ---- main: T = skt @ w. BM=256 BN=128 BK=32, 2-buffer; A converted in-kernel
// from f32 skt (no sktb pre-pass); B staged from wb via global_load_lds.
// 512 threads = 8 waves (4M x 2N), per-wave 64x64 output.
// Per buffer (24KB): A [4 kslot][256 m][16B] = 16K; B [4][128][16B] = 8K.
template <bool PRE>
__global__ __launch_bounds__(512, 4) void hofel_main(
    const float* __restrict__ skt, const float* __restrict__ imgp,
    const float* __restrict__ imgn, const float* __restrict__ w,
    const u16* __restrict__ wb, const float* __restrict__ colsum,
    float* __restrict__ rowacc) {
  __shared__ u16 ldsT[2][12288];  // 2 x 24KB; reused as epilogue scratch
  __shared__ float lds_cs[128];

  const int t = threadIdx.x;
  const int lane = t & 63;
  const int wid = t >> 6;  // 0..7
  const int l15 = lane & 15;
  const int l4 = lane >> 4;

  // XCD swizzle: XCD x gets swz [x*64,(x+1)*64) = mts [x*8,x*8+8), all 8 nt each.
  // All 8 nt-blocks of an mt run on one XCD -> skt k-window stays L2-resident.
  const int swz = (blockIdx.x & 7) * 64 + (blockIdx.x >> 3);
  const int mt = swz >> 3, nt = swz & 7;
  const int m0 = mt * 256, n0 = nt * 128;

  const int wr = wid >> 1, wc = wid & 1;
  const int wm = wr * 64, wn = wc * 64;

  const int sm = t >> 1, sh = t & 1;  // A staging: row m0+sm, k-half sh

  f4v acc[4][4];
#pragma unroll
  for (int mi = 0; mi < 4; ++mi)
#pragma unroll
    for (int ni = 0; ni < 4; ++ni) {
      f4v z = {0.f, 0.f, 0.f, 0.f};
      acc[mi][ni] = z;
    }

  float4 A0r, A1r, A2r, A3r;  // T14: f32 A regs issued early, converted late

  auto stage_loadA = [&](int kt) {
    const float* ap = skt + (size_t)(m0 + sm) * FDIM + kt * 32 + sh * 16;
    A0r = *(const float4*)(ap);
    A1r = *(const float4*)(ap + 4);
    A2r = *(const float4*)(ap + 8);
    A3r = *(const float4*)(ap + 12);
  };

  auto stage_writeA = [&](int buf) {
    u16x8 w0, w1;
    w0[0] = f2bf(A0r.x); w0[1] = f2bf(A0r.y); w0[2] = f2bf(A0r.z); w0[3] = f2bf(A0r.w);
    w0[4] = f2bf(A1r.x); w0[5] = f2bf(A1r.y); w0[6] = f2bf(A1r.z); w0[7] = f2bf(A1r.w);
    w1[0] = f2bf(A2r.x); w1[1] = f2bf(A2r.y); w1[2] = f2bf(A2r.z); w1[3] = f2bf(A2r.w);
    w1[4] = f2bf(A3r.x); w1[5] = f2bf(A3r.y); w1[6] = f2bf(A3r.z); w1[7] = f2bf(A3r.w);
    // kslot (2*sh+q) at row sm: conflict-measured-0 pattern (r4)
    *(u16x8*)((char*)ldsT[buf] + (sh * 2 + 0) * 4096 + sm * 16) = w0;
    *(u16x8*)((char*)ldsT[buf] + (sh * 2 + 1) * 4096 + sm * 16) = w1;
  };

  auto stageB = [&](int buf, int kt) {
    if constexpr (PRE) {
      const int o = wid * 1024;  // wave-uniform; 8 waves cover 8KB
      const int ol = o + lane * 16;
      const int s = ol >> 11;             // kslot 0..3
      const int n = (ol >> 4) & 127;
      gload_lds16((const char*)(wb + ((size_t)(kt * 4 + s) * FDIM + n0 + n) * 8),
                  (char*)ldsT[buf] + 16384 + o);
    } else {
      // no-workspace fallback: build B from f32 w (strided, correct, slow)
      const int kc = t >> 2, s = t & 3;
      const float* wr_ = w + (size_t)(n0 + kc) * FDIM + kt * 32 + s * 8;
      const float4 a = *(const float4*)(wr_);
      const float4 b = *(const float4*)(wr_ + 4);
      u16x8 pk;
      pk[0] = f2bf(a.x); pk[1] = f2bf(a.y); pk[2] = f2bf(a.z); pk[3] = f2bf(a.w);
      pk[4] = f2bf(b.x); pk[5] = f2bf(b.y); pk[6] = f2bf(b.z); pk[7] = f2bf(b.w);
      *(u16x8*)((char*)ldsT[buf] + 16384 + (s * 128 + kc) * 16) = pk;
    }
  };

  // ---- prologue ----
  if (t < 128) lds_cs[t] = colsum[n0 + t];
  stage_loadA(0);
  stageB(0, 0);
  stage_writeA(0);
  __syncthreads();  // tile 0 ready (drains vmcnt + lgkm)

  int cur = 0;
  for (int kt = 0; kt < 32; ++kt) {
    if (kt < 31) { stage_loadA(kt + 1); stageB(cur ^ 1, kt + 1); }  // issue early

    const char* bufb = (const char*)ldsT[cur];
    bf8v aF[4], bF[4];
#pragma unroll
    for (int mi = 0; mi < 4; ++mi)
      aF[mi] = *(const bf8v*)(bufb + l4 * 4096 + (wm + mi * 16 + l15) * 16);
#pragma unroll
    for (int ni = 0; ni < 4; ++ni)
      bF[ni] = *(const bf8v*)(bufb + 16384 + l4 * 2048 + (wn + ni * 16 + l15) * 16);
#pragma unroll
    for (int mi = 0; mi < 4; ++mi)
#pragma unroll
      for (int ni = 0; ni < 4; ++ni)
        acc[mi][ni] = __builtin_amdgcn_mfma_f32_16x16x32_bf16(aF[mi], bF[ni], acc[mi][ni], 0, 0, 0);

    if (kt < 31) stage_writeA(cur ^ 1);  // convert+write after MFMAs (loads landed)
    __syncthreads();
    cur ^= 1;
  }

  // ---- epilogue (r8-validated): per-wave LDS transpose -> coalesced f4 reads
  // rowacc[row] += sum_c (p-n)*(-2*T + (p+n)*colsum[c]),  c in [n0+wn, +64)
  {
    float(*eT)[68] = (float(*)[68])((char*)ldsT + wid * 4352);  // per-wave 16x68
    const int r = l15;
    const int qb = l4;
#pragma unroll
    for (int mi = 0; mi < 4; ++mi) {
#pragma unroll
      for (int ni = 0; ni < 4; ++ni)
#pragma unroll
        for (int rr = 0; rr < 4; ++rr)
          eT[l4 * 4 + rr][ni * 16 + l15] = acc[mi][ni][rr];
      // within-wave LDS RAW: compiler inserts the lgkm wait; no barrier needed
      const int rowg = m0 + wm + mi * 16 + r;
      const float* pr = imgp + (size_t)rowg * FDIM + n0 + wn;
      const float* nr = imgn + (size_t)rowg * FDIM + n0 + wn;
      float part = 0.f;
#pragma unroll
      for (int i = 0; i < 4; ++i) {
        const int q = qb + 4 * i;  // col-quad 0..15
        const f4v T = *(const f4v*)&eT[r][q * 4];
        const float4 p = *(const float4*)(pr + q * 4);
        const float4 n = *(const float4*)(nr + q * 4);
        const f4v cs = *(const f4v*)&lds_cs[wn + q * 4];
        part += (p.x - n.x) * (-2.f * T[0] + (p.x + n.x) * cs[0]);
        part += (p.y - n.y) * (-2.f * T[1] + (p.y + n.y) * cs[1]);
        part += (p.z - n.z) * (-2.f * T[2] + (p.z + n.z) * cs[2]);
        part += (p.w - n.w) * (-2.f * T[3] + (p.w + n.w) * cs[3]);
      }
      part += __shfl_xor(part, 16);
      part += __shfl_xor(part, 32);
      if (lane < 16) atomicAdd(rowacc + rowg, part);
      __syncthreads();  // keep waves' scratch phases aligned (r8 pattern)
    }
  }
}

__global__ __launch_bounds__(1024) void hinge_reduce(const float* __restrict__ rowacc,
                                                     float* __restrict__ wsf) {
  __shared__ float part[16];
  const int t = threadIdx.x;
  const int id = blockIdx.x * 1024 + t;
  float v = fmaxf(DELTA_C + rowacc[id], 0.f);
#pragma unroll
  for (int off = 1; off < 64; off <<= 1) v += __shfl_xor(v, off);
  if ((t & 63) == 0) part[t >> 6] = v;
  __syncthreads();
  if (t < 16) {
    float x = part[t];
#pragma unroll
    for (int off = 1; off < 16; off <<= 1) x += __shfl_xor(x, off);
    if (t == 0) atomicAdd(&wsf[0], x);
  }
}

__global__ __launch_bounds__(128) void finalize_k(const float* __restrict__ wsf,
                                                  const float* __restrict__ pabs,
                                                  const float* __restrict__ psq,
                                                  float* __restrict__ out) {
  __shared__ float ra[2], rs[2];
  const int t = threadIdx.x;
  float a = pabs[t], s = psq[t];
#pragma unroll
  for (int off = 1; off < 64; off <<= 1) {
    a += __shfl_xor(a, off);
    s += __shfl_xor(s, off);
  }
  if ((t & 63) == 0) { ra[t >> 6] = a; rs[t >> 6] = s; }
  __syncthreads();
  if (t == 0)
    out[0] = wsf[0] * (1.f / (float)BROWS) +
             LAMB_C * ((ra[0] + ra[1]) + sqrtf(rs[0] + rs[1]));
}

extern "C" void kernel_launch(void* const* d_in, const int* in_sizes, int n_in,
                              void* d_out, int out_size, void* d_ws, size_t ws_size,
                              hipStream_t stream) {
  const float* skt  = (const float*)d_in[0];
  const float* imgp = (const float*)d_in[1];
  const float* imgn = (const float*)d_in[2];
  const float* w    = (const float*)d_in[3];

  float* wsf = (float*)d_ws;
  float* colsum = wsf + 16;
  float* pabs = (float*)((char*)d_ws + WS_PABS_OFF);
  float* psq = (float*)((char*)d_ws + WS_PSQ_OFF);
  float* rowacc = (float*)((char*)d_ws + WS_ROWACC_OFF);
  u16* wb = (u16*)((char*)d_ws + WS_WB_OFF);
  float* out = (float*)d_out;

  // zero wsf + colsum + pabs/psq + rowacc every call (harness doesn't re-poison)
  hipMemsetAsync(d_ws, 0, WS_ROWACC_OFF + BROWS * sizeof(float), stream);

  prep_w<<<128, 256, 0, stream>>>(w, colsum, pabs, psq, wb);

  if (ws_size >= WS_NEED) {
    hofel_main<true><<<512, 512, 0, stream>>>(skt, imgp, imgn, w, wb, colsum, rowacc);
  } else {
    hofel_main<false><<<512, 512, 0, stream>>>(skt, imgp, imgn, w, wb, colsum, rowacc);
  }

  hinge_reduce<<<16, 1024, 0, stream>>>(rowacc, wsf);
  finalize_k<<<1, 128, 0, stream>>>(wsf, pabs, psq, out);
}